// Round 9
// baseline (161.012 us; speedup 1.0000x reference)
//
#include <hip/hip_runtime.h>
#include <hip/hip_bf16.h>
#include <hip/hip_fp16.h>

// Problem constants
#define GN 28
#define CH 3                 // g-tiles per chunk
#define NCH 10               // ceil(28/3): chunks 0..8 full, chunk 9 has g=27 only
// ws layout: per-g contiguous 12288-byte tile, pre-swizzled for LDS staging:
//   [ W1 f16 [n=64][k=64] 8KiB | W2 f16 [n2=32][kk=64] K-permuted 4KiB ]
// byte = n*128 + 2k, XOR-swizzled ^((n&7)<<4)   (byte-identical to r2..r8 layout)
#define G_TILE_BYTES 12288
#define WS_BYTES (GN * G_TILE_BYTES)   // 344064

typedef __attribute__((ext_vector_type(4))) float f32x4;
typedef __attribute__((ext_vector_type(8))) short short8;
typedef _Float16 f16x8 __attribute__((ext_vector_type(8)));
typedef __fp16 pk16x2 __attribute__((ext_vector_type(2)));   // cvt_pkrtz result type

__device__ __forceinline__ unsigned short f2h(float v){
  __half h = __float2half(v);   // RNE
  return __builtin_bit_cast(unsigned short, h);
}
__device__ __forceinline__ f32x4 mfma16f(short8 a, short8 b, f32x4 c){
  return __builtin_amdgcn_mfma_f32_16x16x32_f16(
      __builtin_bit_cast(f16x8, a), __builtin_bit_cast(f16x8, b), c, 0, 0, 0);
}

// ---------------------------------------------------------------------------
// Prologue (unchanged, hardware-verified since r4): one block per g,
// coalesced reads, LDS transpose (+1 pad), packed uint4 swizzle-safe stores.
// W2 K-permuted so layer-1 D-fragments feed layer-2 B directly:
//   MFMA k-slot kk = ks*32 + q*8 + u*4 + i  carries  kn = 32*ks + 16*u + 4*q + i
// ---------------------------------------------------------------------------
__global__ __launch_bounds__(256) void prep_weights(
    const float* __restrict__ W1, const float* __restrict__ W2,
    unsigned char* __restrict__ ws){
  __shared__ float t1[64*65];   // W1[g] transposed staging, padded
  __shared__ float t2[64*33];   // W2[g] staging, padded
  const int g = blockIdx.x;
  const int tid = threadIdx.x;

  {
    const f32x4* src = (const f32x4*)(W1 + g*4096);
    int k = tid >> 2, n0 = (tid & 3) * 16;
    #pragma unroll
    for (int j = 0; j < 4; ++j){
      f32x4 v = src[tid*4 + j];
      #pragma unroll
      for (int e = 0; e < 4; ++e) t1[k*65 + n0 + j*4 + e] = v[e];
    }
  }
  {
    const f32x4* src = (const f32x4*)(W2 + g*2048);
    int k = tid >> 2, n0 = (tid & 3) * 8;
    #pragma unroll
    for (int j = 0; j < 2; ++j){
      f32x4 v = src[tid*2 + j];
      #pragma unroll
      for (int e = 0; e < 4; ++e) t2[k*33 + n0 + j*4 + e] = v[e];
    }
  }
  __syncthreads();

  unsigned char* base = ws + g*G_TILE_BYTES;
  {
    int n = tid & 63, mh = tid >> 6;
    #pragma unroll
    for (int h = 0; h < 2; ++h){
      unsigned w[4];
      #pragma unroll
      for (int mm = 0; mm < 4; ++mm){
        int m = mh*8 + h*4 + mm;          // k-pair index
        float lo = t1[(2*m    )*65 + n];
        float hi = t1[(2*m + 1)*65 + n];
        w[mm] = (unsigned)f2h(lo) | ((unsigned)f2h(hi) << 16);
      }
      int off = (n*128 + mh*32 + h*16) ^ ((n & 7) << 4);
      *(uint4*)(base + off) = make_uint4(w[0], w[1], w[2], w[3]);
    }
  }
  {
    int n2 = tid & 31, mq = tid >> 5;
    unsigned w[4];
    #pragma unroll
    for (int mm = 0; mm < 4; ++mm){
      int m = mq*4 + mm;
      int kk = 2*m;
      int ks = kk >> 5, qq = (kk >> 3) & 3, u = (kk >> 2) & 1, i = kk & 3;
      int kn = 32*ks + 16*u + 4*qq + i;   // kk,kk+1 -> kn,kn+1
      float lo = t2[(kn    )*33 + n2];
      float hi = t2[(kn + 1)*33 + n2];
      w[mm] = (unsigned)f2h(lo) | ((unsigned)f2h(hi) << 16);
    }
    int off = (n2*128 + mq*16) ^ ((n2 & 7) << 4);
    *(uint4*)(base + 8192 + off) = make_uint4(w[0], w[1], w[2], w[3]);
  }
}

// ---------------------------------------------------------------------------
// Main fused kernel, round 9: COARSE SYNC CADENCE. r8's per-g arithmetic,
// but weights double-buffered in CHUNKS of 3 g-tiles (2 x 36 KiB). Per chunk:
// stage next 3 tiles, compute 3 branches with NO barrier between them (one
// big scheduling region -> compiler hoists bias loads / pipelines across g),
// then a single vmcnt(0)+barrier. 28 sync events -> 10. Results via tiny
// double-buffered outb[2][128][CH] with per-chunk writeout.
// 1024 blocks x 256 threads, 128 rows/block, 32 rows/wave, LDS 75 KiB ->
// 2 blocks/CU, 16 waves/CU (TLP equal to r8: single-variable experiment).
// ---------------------------------------------------------------------------
__global__ __launch_bounds__(256, 2) void mlp_fused(
    const float* __restrict__ x,  const float* __restrict__ b1,
    const float* __restrict__ b2, const float* __restrict__ W3,
    const float* __restrict__ b3, const unsigned char* __restrict__ ws,
    float* __restrict__ out){
  __shared__ uint4 wbuf[2][CH*768];     // 2 x 36 KiB weight chunk
  __shared__ float outb[2][128*CH];     // 2 x 1.5 KiB result staging

  const int tid = threadIdx.x;
  const int wv  = tid >> 6;
  const int ln  = tid & 63;
  const int l15 = ln & 15;
  const int q   = ln >> 4;
  const int rowBase = blockIdx.x * 128 + wv * 32;

  // ---- x B-fragments (f16), loaded once, reused for all 28 g ----
  short8 xf[2][2];
  #pragma unroll
  for (int rt = 0; rt < 2; ++rt)
    #pragma unroll
    for (int ks = 0; ks < 2; ++ks){
      const float* p = x + (rowBase + rt*16 + l15)*64 + ks*32 + q*8;
      f32x4 a = *(const f32x4*)p;
      f32x4 b = *(const f32x4*)(p + 4);
      short8 s;
      #pragma unroll
      for (int j = 0; j < 4; ++j){
        s[j]   = (short)f2h(a[j]);
        s[4+j] = (short)f2h(b[j]);
      }
      xf[rt][ks] = s;
    }

  // ---- hoisted swizzled fragment offsets (g-invariant, uint4 units, within tile) ----
  int offA1[4][2], offA2[2][2];
  #pragma unroll
  for (int nt = 0; nt < 4; ++nt)
    #pragma unroll
    for (int ks = 0; ks < 2; ++ks){
      int n = nt*16 + l15;
      offA1[nt][ks] = ((n*128 + ks*64 + q*16) ^ ((n & 7) << 4)) >> 4;
    }
  #pragma unroll
  for (int nt = 0; nt < 2; ++nt)
    #pragma unroll
    for (int ks = 0; ks < 2; ++ks){
      int n2 = nt*16 + l15;
      offA2[nt][ks] = (((n2*128 + ks*64 + q*16) ^ ((n2 & 7) << 4)) >> 4) + 512;
    }

  // ---- stage one chunk: wave wv copies its 3 KiB slice of each tile ----
  auto stageChunk = [&](int ch, int buf){
    #pragma unroll
    for (int t = 0; t < CH; ++t){
      int g = ch*CH + t;
      if (g < GN){
        const unsigned char* gb = ws + g*G_TILE_BYTES + wv*3072 + ln*16;
        uint4* lb = &wbuf[buf][t*768 + wv*192];
        #pragma unroll
        for (int it = 0; it < 3; ++it){
          __builtin_amdgcn_global_load_lds(
              (const __attribute__((address_space(1))) void*)(gb + it*1024),
              (__attribute__((address_space(3))) void*)(lb + it*64), 16, 0, 0);
        }
      }
    }
  };

  // relu + f32->f16 pack (pkrtz pairs, r7-verified), h[0..3]<-v0, h[4..7]<-v1
  auto packrelu = [&](const f32x4& v0, const f32x4& v1) -> short8 {
    union { unsigned u[4]; short8 s; } r;
    pk16x2 t0 = __builtin_amdgcn_cvt_pkrtz(fmaxf(v0[0],0.f), fmaxf(v0[1],0.f));
    pk16x2 t1 = __builtin_amdgcn_cvt_pkrtz(fmaxf(v0[2],0.f), fmaxf(v0[3],0.f));
    pk16x2 t2 = __builtin_amdgcn_cvt_pkrtz(fmaxf(v1[0],0.f), fmaxf(v1[1],0.f));
    pk16x2 t3 = __builtin_amdgcn_cvt_pkrtz(fmaxf(v1[2],0.f), fmaxf(v1[3],0.f));
    r.u[0] = __builtin_bit_cast(unsigned, t0);
    r.u[1] = __builtin_bit_cast(unsigned, t1);
    r.u[2] = __builtin_bit_cast(unsigned, t2);
    r.u[3] = __builtin_bit_cast(unsigned, t3);
    return r.s;
  };

  // ---- prologue: stage chunk 0 ----
  stageChunk(0, 0);
  asm volatile("s_waitcnt vmcnt(0)" ::: "memory");
  __syncthreads();

  for (int ch = 0; ch < NCH; ++ch){
    const int cur = ch & 1;
    if (ch + 1 < NCH) stageChunk(ch + 1, cur ^ 1);
    const uint4* wb = wbuf[cur];
    float* ob = &outb[cur][0];

    // -------- compute CH branches, barrier-free (one scheduling region) --------
    #pragma unroll
    for (int t = 0; t < CH; ++t){
      const int g = ch*CH + t;
      if (g >= GN) continue;            // only trims chunk 9
      const uint4* wt = wb + t*768;

      // layer-1 bias C-operands (L1/L2-hot, compiler hoists across t)
      f32x4 b1v[4];
      #pragma unroll
      for (int nt = 0; nt < 4; ++nt)
        b1v[nt] = *(const f32x4*)(b1 + g*64 + nt*16 + q*4);

      // ---------------- layer 1: h1T[n=64][r=32/wave] ----------------
      short8 a1[4][2];
      #pragma unroll
      for (int nt = 0; nt < 4; ++nt)
        #pragma unroll
        for (int ks = 0; ks < 2; ++ks)
          a1[nt][ks] = __builtin_bit_cast(short8, wt[offA1[nt][ks]]);
      f32x4 acc1[4][2];
      #pragma unroll
      for (int nt = 0; nt < 4; ++nt)
        #pragma unroll
        for (int rt = 0; rt < 2; ++rt){
          acc1[nt][rt] = mfma16f(a1[nt][0], xf[rt][0], b1v[nt]);
          acc1[nt][rt] = mfma16f(a1[nt][1], xf[rt][1], acc1[nt][rt]);
        }

      f32x4 b2v[2], w3v[2];
      #pragma unroll
      for (int nt = 0; nt < 2; ++nt){
        b2v[nt] = *(const f32x4*)(b2 + g*32 + nt*16 + q*4);
        w3v[nt] = *(const f32x4*)(W3 + g*32 + nt*16 + q*4);
      }

      // ---- h1 relu -> f16, packed IN REGISTERS as layer-2 B-frags ----
      // k-slot (ks, q*8+u*4+i) carries n = 32ks+16u+4q+i == acc1[2ks+u][rt][i]
      short8 bh[2][2];
      #pragma unroll
      for (int rt = 0; rt < 2; ++rt)
        #pragma unroll
        for (int ks = 0; ks < 2; ++ks)
          bh[rt][ks] = packrelu(acc1[2*ks][rt], acc1[2*ks + 1][rt]);

      // ---------------- layer 2: h2T[n2=32][r=32/wave] ----------------
      short8 a2[2][2];
      #pragma unroll
      for (int nt = 0; nt < 2; ++nt)
        #pragma unroll
        for (int ks = 0; ks < 2; ++ks)
          a2[nt][ks] = __builtin_bit_cast(short8, wt[offA2[nt][ks]]);
      f32x4 acc2[2][2];
      #pragma unroll
      for (int nt = 0; nt < 2; ++nt)
        #pragma unroll
        for (int rt = 0; rt < 2; ++rt){
          acc2[nt][rt] = mfma16f(a2[nt][0], bh[rt][0], b2v[nt]);
          acc2[nt][rt] = mfma16f(a2[nt][1], bh[rt][1], acc2[nt][rt]);
        }

      // ---------------- layer 3: dot + quarter-reduce -> outb ----------------
      float bias3 = b3[g];
      #pragma unroll
      for (int rt = 0; rt < 2; ++rt){
        float p = 0.0f;
        #pragma unroll
        for (int nt = 0; nt < 2; ++nt)
          #pragma unroll
          for (int i = 0; i < 4; ++i)
            p = fmaf(fmaxf(acc2[nt][rt][i], 0.0f), w3v[nt][i], p);
        p += __shfl_xor(p, 16);
        p += __shfl_xor(p, 32);
        p += bias3;
        if (ln < 16)
          ob[(wv*32 + rt*16 + ln)*CH + t] = p;   // stride-3 words: conflict-free
      }
    }

    // one drain+barrier per CHUNK: next chunk staged, outb[cur] complete,
    // previous writeout's stores drained.
    asm volatile("s_waitcnt vmcnt(0)" ::: "memory");
    __syncthreads();

    // -------- writeout chunk ch (reads outb[cur]; next compute uses cur^1) --------
    {
      const int g0 = ch*CH;
      const int nc = (GN - g0 < CH) ? (GN - g0) : CH;
      if (tid < 128){
        float* dst = out + (blockIdx.x*128 + tid)*GN + g0;
        const float* src = &outb[cur][tid*CH];
        #pragma unroll
        for (int c = 0; c < CH; ++c)
          if (c < nc) dst[c] = src[c];
      }
    }
  }
}

extern "C" void kernel_launch(void* const* d_in, const int* in_sizes, int n_in,
                              void* d_out, int out_size, void* d_ws, size_t ws_size,
                              hipStream_t stream){
  const float* x  = (const float*)d_in[0];
  const float* W1 = (const float*)d_in[1];
  const float* b1 = (const float*)d_in[2];
  const float* W2 = (const float*)d_in[3];
  const float* b2 = (const float*)d_in[4];
  const float* W3 = (const float*)d_in[5];
  const float* b3 = (const float*)d_in[6];
  unsigned char* ws = (unsigned char*)d_ws;
  float* out = (float*)d_out;
  if (ws_size < (size_t)WS_BYTES) return;
  hipLaunchKernelGGL(prep_weights, dim3(GN), dim3(256), 0, stream, W1, W2, ws);
  hipLaunchKernelGGL(mlp_fused, dim3(1024), dim3(256), 0, stream,
                     x, b1, b2, W3, b3, ws, out);
}